// Round 5
// baseline (492.309 us; speedup 1.0000x reference)
//
#include <hip/hip_runtime.h>
#include <hip/hip_bf16.h>

typedef unsigned short u16;
typedef float f32x4 __attribute__((ext_vector_type(4)));
typedef __bf16 bf16x8 __attribute__((ext_vector_type(8)));

constexpr int TSEQ = 4096;   // sequence length
constexpr int DMOD = 4096;   // d_model
constexpr int HID  = 2048;   // d_hidden
constexpr int HID2 = 4096;   // 2*HID (re/im planes)
constexpr int NCH  = 128;    // scan chunks
constexpr int CHL  = 32;     // chunk length (NCH*CHL == TSEQ)

// ---------- helpers ----------
__device__ __forceinline__ u16 f2bf(float f) {
  unsigned u = __builtin_bit_cast(unsigned, f);
  u += 0x7fffu + ((u >> 16) & 1u);   // RNE
  return (u16)(u >> 16);
}
__device__ __forceinline__ float bf2f(u16 u) {
  return __builtin_bit_cast(float, (unsigned)u << 16);
}
__device__ __forceinline__ unsigned pack2(float a, float b) {
  return (unsigned)f2bf(a) | ((unsigned)f2bf(b) << 16);
}
__device__ __forceinline__ void load_lds16(const u16* g, u16* l) {
  __builtin_amdgcn_global_load_lds((const __attribute__((address_space(1))) void*)g,
                                   (__attribute__((address_space(3))) void*)l,
                                   16, 0, 0);
}
__device__ __forceinline__ unsigned lds_addr(const u16* p) {
  return (unsigned)(uintptr_t)(const __attribute__((address_space(3))) u16*)p;
}

// ---------- prep kernels ----------
__global__ __launch_bounds__(256) void k_lambda(const float* __restrict__ nu_log,
                                                const float* __restrict__ theta_log,
                                                float* __restrict__ lam_re, float* __restrict__ lam_im,
                                                float* __restrict__ lamL_re, float* __restrict__ lamL_im) {
  int h = blockIdx.x * 256 + threadIdx.x;
  if (h >= HID) return;
  float nu = expf(nu_log[h]);
  float th = expf(theta_log[h]);
  float mag = expf(-nu);
  float lr = mag * cosf(th), li = mag * sinf(th);
  lam_re[h] = lr; lam_im[h] = li;
  float pr = lr, pi = li;
#pragma unroll
  for (int i = 0; i < 5; ++i) {   // lam^32 via 5 squarings (CHL = 32)
    float nr = pr * pr - pi * pi;
    float ni = 2.f * pr * pi;
    pr = nr; pi = ni;
  }
  lamL_re[h] = pr; lamL_im[h] = pi;
}

__global__ __launch_bounds__(256) void k_cast_x(const float* __restrict__ x, u16* __restrict__ xb) {
  size_t i = ((size_t)blockIdx.x * 256 + threadIdx.x) * 4;
  float4 v = *reinterpret_cast<const float4*>(x + i);
  uint2 o;
  o.x = pack2(v.x, v.y);
  o.y = pack2(v.z, v.w);
  *reinterpret_cast<uint2*>(xb + i) = o;
}

__global__ __launch_bounds__(256) void k_make_bcat(const float* __restrict__ Bre, const float* __restrict__ Bim,
                                                   const float* __restrict__ gamma_log, u16* __restrict__ Bcat) {
  int idx = blockIdx.x * 256 + threadIdx.x;
  int h  = idx / (DMOD / 4);
  int dv = (idx % (DMOD / 4)) * 4;
  float g = expf(gamma_log[h]);
  float4 r  = *reinterpret_cast<const float4*>(Bre + (size_t)h * DMOD + dv);
  float4 im = *reinterpret_cast<const float4*>(Bim + (size_t)h * DMOD + dv);
  uint2 orr; orr.x = pack2(r.x * g, r.y * g); orr.y = pack2(r.z * g, r.w * g);
  *reinterpret_cast<uint2*>(Bcat + (size_t)h * DMOD + dv) = orr;
  uint2 oim; oim.x = pack2(im.x * g, im.y * g); oim.y = pack2(im.z * g, im.w * g);
  *reinterpret_cast<uint2*>(Bcat + (size_t)(h + HID) * DMOD + dv) = oim;
}

__global__ __launch_bounds__(256) void k_make_ccat(const float* __restrict__ Cre, const float* __restrict__ Cim,
                                                   u16* __restrict__ Ccat) {
  int idx = blockIdx.x * 256 + threadIdx.x;
  int d  = idx / (HID / 4);
  int hv = (idx % (HID / 4)) * 4;
  float4 r  = *reinterpret_cast<const float4*>(Cre + (size_t)d * HID + hv);
  float4 im = *reinterpret_cast<const float4*>(Cim + (size_t)d * HID + hv);
  uint2 orr; orr.x = pack2(r.x, r.y); orr.y = pack2(r.z, r.w);
  *reinterpret_cast<uint2*>(Ccat + (size_t)d * HID2 + hv) = orr;
  uint2 oim; oim.x = pack2(-im.x, -im.y); oim.y = pack2(-im.z, -im.w);
  *reinterpret_cast<uint2*>(Ccat + (size_t)d * HID2 + HID + hv) = oim;
}

// ---------- 256^2 8-phase GEMM: C(4096x4096) = A(4096x4096) @ Bt(4096x4096)^T ----------
// 8 waves (2M x 4N), BK=64, 128 KiB LDS double-buffer, swizzled LDS, counted vmcnt,
// 1-phase-lookahead ds_reads with counted lgkmcnt (DS drains under MFMA).
#define DSR(d, a, IMM) asm volatile("ds_read_b128 %0, %1 offset:" IMM : "=v"(d) : "v"(a))

#define RD_A(AF, B, O0, O1, O2, O3) do { \
  DSR(AF[0][0], aAk0[B], O0); DSR(AF[0][1], aAk1[B], O0); \
  DSR(AF[1][0], aAk0[B], O1); DSR(AF[1][1], aAk1[B], O1); \
  DSR(AF[2][0], aAk0[B], O2); DSR(AF[2][1], aAk1[B], O2); \
  DSR(AF[3][0], aAk0[B], O3); DSR(AF[3][1], aAk1[B], O3); } while (0)

#define RD_B(B, DST, O0, O1) do { \
  DSR(DST[0][0], aBk0[B], O0); DSR(DST[0][1], aBk1[B], O0); \
  DSR(DST[1][0], aBk0[B], O1); DSR(DST[1][1], aBk1[B], O1); } while (0)

#define STAGE_A(b, h, kb) do { const u16* _s = stA + (size_t)(h) * 128 * 4096 + (kb); \
  load_lds16(_s, dA[b][h]); load_lds16(_s + 64 * 4096, dA[b][h] + 4096); } while (0)
#define STAGE_B(b, h, kb) do { const u16* _s = stB + (size_t)(h) * 128 * 4096 + (kb); \
  load_lds16(_s, dB[b][h]); load_lds16(_s + 64 * 4096, dB[b][h] + 4096); } while (0)

#define MMQ(AF, MB, NB, BF) do { \
  _Pragma("unroll") for (int k = 0; k < 2; ++k) { \
  _Pragma("unroll") for (int m = 0; m < 4; ++m) { \
  _Pragma("unroll") for (int n = 0; n < 2; ++n) { \
    acc[(MB)+m][(NB)+n] = __builtin_amdgcn_mfma_f32_16x16x32_bf16(AF[m][k], BF[n][k], acc[(MB)+m][(NB)+n], 0, 0, 0); } } } } while (0)

#define MIDN(CNT) do { __builtin_amdgcn_s_barrier(); \
  asm volatile("s_waitcnt lgkmcnt(" CNT ")"); \
  __builtin_amdgcn_sched_barrier(0); \
  __builtin_amdgcn_s_setprio(1); } while (0)
#define ENDP() do { __builtin_amdgcn_s_setprio(0); \
  __builtin_amdgcn_s_barrier(); } while (0)
#define ENDPV() do { __builtin_amdgcn_s_setprio(0); \
  asm volatile("s_waitcnt vmcnt(4)"); \
  __builtin_amdgcn_s_barrier(); } while (0)

template <bool EPI>
__global__ __launch_bounds__(512, 2) void gemm8(const u16* __restrict__ A, const u16* __restrict__ Bt,
                                                void* __restrict__ Cout,
                                                const float* __restrict__ resid,
                                                const float* __restrict__ dvec) {
  constexpr int K = 4096, N = 4096;
  constexpr int NI = (K / 64) / 2;   // 32 iterations, 2 K-tiles each
  __shared__ __align__(16) u16 L[65536];   // 128 KiB

  int nwg = gridDim.x;                       // 256 (16x16), %8==0
  int wg = blockIdx.x;
  wg = (wg & 7) * (nwg >> 3) + (wg >> 3);    // XCD-chunked swizzle (bijective)
  int bm = (wg >> 4) << 8;
  int bn = (wg & 15) << 8;

  int tid = threadIdx.x;
  int lane = tid & 63;
  int wave = tid >> 6;
  int wm = wave >> 2, wn = wave & 3;
  int l15 = lane & 15, g = lane >> 4;

  // ds_read addresses (swizzle: byte ^= (row&7)<<4)
  unsigned offk0 = (unsigned)(((unsigned)g << 4) ^ ((unsigned)(lane & 7) << 4));
  unsigned offk1 = offk0 ^ 64u;
  unsigned aAk0[2], aAk1[2], aBk0[2], aBk1[2];
#pragma unroll
  for (int b = 0; b < 2; ++b) {
    unsigned ab = lds_addr(&L[b * 32768 + wm * 8192 + l15 * 64]);
    aAk0[b] = ab + offk0; aAk1[b] = ab + offk1;
    unsigned bb = lds_addr(&L[b * 32768 + 16384 + (wn >> 1) * 8192 + (wn & 1) * 4096 + l15 * 64]);
    aBk0[b] = bb + offk0; aBk1[b] = bb + offk1;
  }

  // staging: thread tid covers (row = tid>>3, chunk = tid&7), source pre-unswizzled
  int trow = tid >> 3;
  int tchk = ((tid & 7) ^ (trow & 7)) << 3;
  const u16* stA = A  + (size_t)(bm + trow) * K + tchk;
  const u16* stB = Bt + (size_t)(bn + trow) * K + tchk;
  u16* dA[2][2]; u16* dB[2][2];
#pragma unroll
  for (int b = 0; b < 2; ++b)
#pragma unroll
    for (int h = 0; h < 2; ++h) {
      dA[b][h] = &L[b * 32768 + h * 8192 + tid * 8];
      dB[b][h] = &L[b * 32768 + 16384 + h * 8192 + tid * 8];
    }

  bf16x8 af1[4][2], af2[4][2], b0[2][2], b1[2][2];
  f32x4 acc[8][4];
#pragma unroll
  for (int i = 0; i < 8; ++i)
#pragma unroll
    for (int n = 0; n < 4; ++n) acc[i][n] = (f32x4){0.f, 0.f, 0.f, 0.f};

  // prologue: tile0 -> buf0 (all 4 halves), tile1 -> buf1 (Bh0, Ah0)
  STAGE_B(0, 0, 0);  STAGE_A(0, 0, 0);
  STAGE_B(0, 1, 0);  STAGE_A(0, 1, 0);
  STAGE_B(1, 0, 64); STAGE_A(1, 0, 64);
  asm volatile("s_waitcnt vmcnt(4)");   // buf0 fully landed; buf1's 2 stages may fly
  __builtin_amdgcn_s_barrier();

#pragma unroll 1
  for (int j = 0; j < NI; ++j) {
    int kb1 = ((2 * j + 1) << 6) & (K - 1);
    int kb2 = ((2 * j + 2) << 6) & (K - 1);
    int kb3 = ((2 * j + 3) << 6) & (K - 1);
    // ---- K-tile 2j (buf0) ----
    // P1: reads af1(8)+b0(4)+b1(4); MFMA needs af1,b0 -> lgkm(4)
    RD_A(af1, 0, "0", "2048", "4096", "6144");
    RD_B(0, b0, "0", "2048");
    RD_B(0, b1, "4096", "6144");
    STAGE_B(1, 1, kb1);
    MIDN("4"); MMQ(af1, 0, 0, b0); ENDP();
    // P2: reads af2(8); MFMA needs b1 -> lgkm(8)
    RD_A(af2, 0, "8192", "10240", "12288", "14336");
    STAGE_A(1, 1, kb1);
    MIDN("8"); MMQ(af1, 0, 2, b1); ENDP();
    // P3: no reads; MFMA needs af2 -> lgkm(0)
    STAGE_B(0, 0, kb2);
    MIDN("0"); MMQ(af2, 4, 2, b1); ENDP();
    // P4
    STAGE_A(0, 0, kb2);
    MIDN("0"); MMQ(af2, 4, 0, b0); ENDPV();
    // ---- K-tile 2j+1 (buf1) ----
    // P5
    RD_A(af1, 1, "0", "2048", "4096", "6144");
    RD_B(1, b0, "0", "2048");
    RD_B(1, b1, "4096", "6144");
    STAGE_B(0, 1, kb2);
    MIDN("4"); MMQ(af1, 0, 0, b0); ENDP();
    // P6
    RD_A(af2, 1, "8192", "10240", "12288", "14336");
    STAGE_A(0, 1, kb2);
    MIDN("8"); MMQ(af1, 0, 2, b1); ENDP();
    // P7
    STAGE_B(1, 0, kb3);
    MIDN("0"); MMQ(af2, 4, 2, b1); ENDP();
    // P8
    STAGE_A(1, 0, kb3);
    MIDN("0"); MMQ(af2, 4, 0, b0); ENDPV();
  }

  // epilogue: C/D mapping col = lane&15, row = (lane>>4)*4 + j
  int crow = bm + wm * 128 + (g << 2);
  int ccol = bn + wn * 64 + l15;
#pragma unroll
  for (int mi = 0; mi < 8; ++mi)
#pragma unroll
    for (int ni = 0; ni < 4; ++ni)
#pragma unroll
      for (int jj = 0; jj < 4; ++jj) {
        int row = crow + mi * 16 + jj;
        int col = ccol + ni * 16;
        float v = acc[mi][ni][jj];
        if constexpr (EPI) {
          v += resid[(size_t)row * N + col] * dvec[col];
          ((float*)Cout)[(size_t)row * N + col] = v;
        } else {
          ((u16*)Cout)[(size_t)row * N + col] = f2bf(v);   // Bu in bf16
        }
      }
}

// ---------- chunked scan over T (Bu bf16, NCH=128 x CHL=32, 2 channels/thread) ----------
__global__ __launch_bounds__(256) void s_chunk_end(const u16* __restrict__ Bu,
                                                   const float* __restrict__ lam_re,
                                                   const float* __restrict__ lam_im,
                                                   float* __restrict__ E) {
  int t = blockIdx.x * 256 + threadIdx.x;     // NCH*HID/2 threads = 512 blocks
  int hp = t & (HID / 2 - 1);
  int c  = t >> 10;
  int h0 = hp << 1;
  float2 lr = *reinterpret_cast<const float2*>(lam_re + h0);
  float2 li = *reinterpret_cast<const float2*>(lam_im + h0);
  float sr0 = 0.f, si0 = 0.f, sr1 = 0.f, si1 = 0.f;
  const u16* base = Bu + (size_t)c * CHL * HID2 + h0;
#pragma unroll 8
  for (int i = 0; i < CHL; ++i) {
    ushort2 vre = *reinterpret_cast<const ushort2*>(base + (size_t)i * HID2);
    ushort2 vim = *reinterpret_cast<const ushort2*>(base + (size_t)i * HID2 + HID);
    float nr0 = lr.x * sr0 - li.x * si0 + bf2f(vre.x);
    float ni0 = lr.x * si0 + li.x * sr0 + bf2f(vim.x);
    float nr1 = lr.y * sr1 - li.y * si1 + bf2f(vre.y);
    float ni1 = lr.y * si1 + li.y * sr1 + bf2f(vim.y);
    sr0 = nr0; si0 = ni0; sr1 = nr1; si1 = ni1;
  }
  *reinterpret_cast<float2*>(E + (size_t)c * HID + h0) = (float2){sr0, sr1};
  *reinterpret_cast<float2*>(E + (size_t)NCH * HID + (size_t)c * HID + h0) = (float2){si0, si1};
}

__global__ __launch_bounds__(256) void s_prefix(const float* __restrict__ lamL_re,
                                                const float* __restrict__ lamL_im,
                                                const float* __restrict__ E,
                                                float* __restrict__ P) {
  int h = blockIdx.x * 256 + threadIdx.x;
  if (h >= HID) return;
  float plr = lamL_re[h], pli = lamL_im[h];
  float pr = 0.f, pi = 0.f;
#pragma unroll 8
  for (int c = 0; c < NCH; ++c) {
    P[(size_t)c * HID + h] = pr;
    P[(size_t)NCH * HID + (size_t)c * HID + h] = pi;
    float er = E[(size_t)c * HID + h];
    float ei = E[(size_t)NCH * HID + (size_t)c * HID + h];
    float nr = plr * pr - pli * pi + er;
    float ni = plr * pi + pli * pr + ei;
    pr = nr; pi = ni;
  }
}

__global__ __launch_bounds__(256) void s_expand(const u16* __restrict__ Bu,
                                                const float* __restrict__ lam_re,
                                                const float* __restrict__ lam_im,
                                                const float* __restrict__ P,
                                                u16* __restrict__ A2) {
  int t = blockIdx.x * 256 + threadIdx.x;
  int hp = t & (HID / 2 - 1);
  int c  = t >> 10;
  int h0 = hp << 1;
  float2 lr = *reinterpret_cast<const float2*>(lam_re + h0);
  float2 li = *reinterpret_cast<const float2*>(lam_im + h0);
  float2 p0 = *reinterpret_cast<const float2*>(P + (size_t)c * HID + h0);
  float2 p1 = *reinterpret_cast<const float2*>(P + (size_t)NCH * HID + (size_t)c * HID + h0);
  float sr0 = p0.x, sr1 = p0.y, si0 = p1.x, si1 = p1.y;
  const u16* base = Bu + (size_t)c * CHL * HID2 + h0;
  u16* ob = A2 + (size_t)c * CHL * HID2 + h0;
#pragma unroll 8
  for (int i = 0; i < CHL; ++i) {
    ushort2 vre = *reinterpret_cast<const ushort2*>(base + (size_t)i * HID2);
    ushort2 vim = *reinterpret_cast<const ushort2*>(base + (size_t)i * HID2 + HID);
    float nr0 = lr.x * sr0 - li.x * si0 + bf2f(vre.x);
    float ni0 = lr.x * si0 + li.x * sr0 + bf2f(vim.x);
    float nr1 = lr.y * sr1 - li.y * si1 + bf2f(vre.y);
    float ni1 = lr.y * si1 + li.y * sr1 + bf2f(vim.y);
    sr0 = nr0; si0 = ni0; sr1 = nr1; si1 = ni1;
    *reinterpret_cast<ushort2*>(ob + (size_t)i * HID2)       = (ushort2){f2bf(sr0), f2bf(sr1)};
    *reinterpret_cast<ushort2*>(ob + (size_t)i * HID2 + HID) = (ushort2){f2bf(si0), f2bf(si1)};
  }
}

// ---------- launch ----------
extern "C" void kernel_launch(void* const* d_in, const int* in_sizes, int n_in,
                              void* d_out, int out_size, void* d_ws, size_t ws_size,
                              hipStream_t stream) {
  const float* inputs    = (const float*)d_in[0];
  const float* nu_log    = (const float*)d_in[1];
  const float* theta_log = (const float*)d_in[2];
  const float* gamma_log = (const float*)d_in[3];
  const float* B_re      = (const float*)d_in[4];
  const float* B_im      = (const float*)d_in[5];
  const float* C_re      = (const float*)d_in[6];
  const float* C_im      = (const float*)d_in[7];
  const float* Dvec      = (const float*)d_in[8];

  char* w = (char*)d_ws;
  u16* xb     = (u16*)w;                              // 33.5 MB; reused as hidden (A2) after G1
  u16* Bcat   = (u16*)(w + (size_t)33554432);         // 33.5 MB; reused as Ccat after G1
  float* lam_re  = (float*)(w + (size_t)67108864);
  float* lam_im  = lam_re + HID;
  float* lamL_re = lam_im + HID;
  float* lamL_im = lamL_re + HID;

  u16* Bu    = (u16*)d_out;      // (T x 2H) bf16 = 33.5 MB, dead before G2 writes
  float* out = (float*)d_out;
  // E/P live in the dead upper half of d_out (67.1 MB total; Bu ends at 33.5 MB)
  float* E = (float*)((char*)d_out + (size_t)40 * 1024 * 1024);   // 2 MB
  float* P = (float*)((char*)d_out + (size_t)44 * 1024 * 1024);   // 2 MB

  k_lambda<<<dim3(HID / 256), dim3(256), 0, stream>>>(nu_log, theta_log, lam_re, lam_im, lamL_re, lamL_im);
  k_cast_x<<<dim3((TSEQ * DMOD / 4) / 256), dim3(256), 0, stream>>>(inputs, xb);
  k_make_bcat<<<dim3((HID * DMOD / 4) / 256), dim3(256), 0, stream>>>(B_re, B_im, gamma_log, Bcat);

  gemm8<false><<<dim3((TSEQ / 256) * (HID2 / 256)), dim3(512), 0, stream>>>(
      xb, Bcat, (void*)Bu, nullptr, nullptr);

  s_chunk_end<<<dim3(NCH * HID / 2 / 256), dim3(256), 0, stream>>>(Bu, lam_re, lam_im, E);
  s_prefix<<<dim3(HID / 256), dim3(256), 0, stream>>>(lamL_re, lamL_im, E, P);
  s_expand<<<dim3(NCH * HID / 2 / 256), dim3(256), 0, stream>>>(Bu, lam_re, lam_im, P, xb /*A2*/);

  k_make_ccat<<<dim3((DMOD * HID / 4) / 256), dim3(256), 0, stream>>>(C_re, C_im, Bcat /*Ccat*/);

  gemm8<true><<<dim3((TSEQ / 256) * (DMOD / 256)), dim3(512), 0, stream>>>(
      xb /*hidden*/, Bcat /*Ccat*/, (void*)out, inputs, Dvec);
}